// Round 5
// baseline (223.725 us; speedup 1.0000x reference)
//
#include <hip/hip_runtime.h>
#include <hip/hip_bf16.h>

// C3 partial connection via MFMA (fp16 in / fp32 acc).
// y = conv5x5(channel-subsets) + bias; out = 1.7159*tanh(2/3*y).
// M = 16 consecutive x-pixels, N = 16 output channels,
// K = (dx, c) with c padded 6->8: k' = dx*8 + c.  Two mfma_f32_16x16x32_f16
// per (output-row, dy): m=0 covers dx0..3, m=1 covers dx4 (rest zero-weighted).
// LDS: channel-interleaved f16 tile [36 rows][20 px][8 ch] -> A-frag is one
// aligned ds_read_b128 per lane. B-frags pre-swizzled per-lane into d_ws.

#define IH 142
#define IW 142
#define OH 138
#define OW 138

typedef _Float16 f16x8 __attribute__((ext_vector_type(8)));
typedef float f32x4 __attribute__((ext_vector_type(4)));

// WIDX[oc][c] = src*64 + block-index, or -1 if oc doesn't consume c.
// src 0=w3(6,3,5,5) 1=w4(9,4,5,5) 2=w6(1,6,5,5); weight elem = blk*25 + dy*5 + dx.
__device__ __constant__ const short WIDX16[16][6] = {
  {   0,    1,    2,   -1,   -1,   -1},   // oc0  {0,1,2}
  {  -1,    3,    4,    5,   -1,   -1},   // oc1  {1,2,3}
  {  -1,   -1,    6,    7,    8,   -1},   // oc2  {2,3,4}
  {  -1,   -1,   -1,    9,   10,   11},   // oc3  {3,4,5}
  {  12,   -1,   -1,   -1,   13,   14},   // oc4  {0,4,5}
  {  15,   16,   -1,   -1,   -1,   17},   // oc5  {0,1,5}
  {64+0, 64+1, 64+2, 64+3,   -1,   -1},   // oc6  {0,1,2,3}
  {  -1, 64+4, 64+5, 64+6, 64+7,   -1},   // oc7  {1,2,3,4}
  {  -1,   -1, 64+8, 64+9, 64+10, 64+11}, // oc8  {2,3,4,5}
  {64+12,  -1,   -1, 64+13, 64+14, 64+15},// oc9  {0,3,4,5}
  {64+16, 64+17, -1,   -1, 64+18, 64+19}, // oc10 {0,1,4,5}
  {64+20, 64+21, 64+22, -1,  -1, 64+23},  // oc11 {0,1,2,5}
  {64+24, 64+25, -1, 64+26, 64+27,  -1},  // oc12 {0,1,3,4}
  {  -1, 64+28, 64+29, -1, 64+30, 64+31}, // oc13 {1,2,4,5}
  {64+32,  -1, 64+33, 64+34, -1, 64+35},  // oc14 {0,2,3,5}
  {128+0, 128+1, 128+2, 128+3, 128+4, 128+5}, // oc15 {0..5}
};

// ---- prep: per-lane pre-swizzled B fragments, 5 dy x 2 m x 64 lanes x 8 halfs ----
// tab[((dy*2+m)*64 + lane)*8 + j] : lane -> (q=lane>>4, oc=lane&15), k = m*32+q*8+j.
__global__ void wprep_kernel(const float* __restrict__ w3, const float* __restrict__ w4,
                             const float* __restrict__ w6, _Float16* __restrict__ tab) {
  int t = blockIdx.x * 256 + threadIdx.x;
  if (t >= 5120) return;
  int j = t & 7, lane = (t >> 3) & 63, dm = t >> 9;
  int dy = dm >> 1, m = dm & 1;
  int q = lane >> 4, oc = lane & 15;
  int k = m * 32 + q * 8 + j;
  int dx = k >> 3, c = k & 7;
  float v = 0.f;
  if (c < 6 && dx < 5) {
    int e = WIDX16[oc][c];
    if (e >= 0) {
      int src = e >> 6, blk = e & 63;
      const float* wp = (src == 0) ? w3 : (src == 1) ? w4 : w6;
      v = wp[blk * 25 + dy * 5 + dx];
    }
  }
  tab[t] = (_Float16)v;
}

__device__ __forceinline__ unsigned int pkh(float a, float b) {
  _Float16 ha = (_Float16)a, hb = (_Float16)b;
  unsigned short ua = __builtin_bit_cast(unsigned short, ha);
  unsigned short ub = __builtin_bit_cast(unsigned short, hb);
  return (unsigned int)ua | ((unsigned int)ub << 16);
}

__device__ __forceinline__ float act(float y) {
  const float TS = 1.9235933878519512f;  // 2*(2/3)*log2(e)
  const float e = __builtin_amdgcn_exp2f(y * TS);
  // A*tanh(S*y) = A - 2A/(exp2(TS*y)+1); saturates correctly at +/-inf.
  return fmaf(-2.f * 1.7159f, __builtin_amdgcn_rcpf(e + 1.f), 1.7159f);
}

// Block: 256 threads = 4 waves; tile 16 px (x) by 32 output rows (8 rows/wave).
// LDS input tile: 36 rows x 20 px x 8 ch halfs (+64B overrun pad).
__global__ __launch_bounds__(256, 3)
void c3_mfma(const float* __restrict__ x,
             const float* __restrict__ b3, const float* __restrict__ b4,
             const float* __restrict__ b6, const _Float16* __restrict__ tab,
             float* __restrict__ out) {
  __shared__ __attribute__((aligned(16))) _Float16 sh[36 * 160 + 32];  // 11584 B

  const int tid = threadIdx.x;
  const int b   = blockIdx.z;
  const int x0  = min((int)blockIdx.x * 16, OW - 16);  // {0,16,...,112,122}
  const int y0  = (int)blockIdx.y * 32;                // {0,32,64,96,128}

  // ---- stage input tile: items = 4 c-pairs x 36 rows x 10 px-pairs ----
  {
    const float* xb = x + (size_t)b * 6 * IH * IW;
    #pragma unroll
    for (int it = 0; it < 6; ++it) {
      int i = it * 256 + tid;
      if (i < 1440) {
        int c2  = i / 360, rem = i - c2 * 360;
        int row = rem / 10, p2 = rem - row * 10;
        int px  = p2 * 2;
        int addr = row * 160 + px * 8 + c2 * 2;  // half index
        if (c2 < 3) {
          int ir = min(y0 + row, IH - 1);
          const float* pa = xb + ((size_t)(2 * c2) * IH + ir) * IW + x0 + px;
          const float* pb = pa + (size_t)IH * IW;
          float2 va = *(const float2*)pa;
          float2 vb = *(const float2*)pb;
          *(unsigned int*)&sh[addr]     = pkh(va.x, vb.x);
          *(unsigned int*)&sh[addr + 8] = pkh(va.y, vb.y);
        } else {  // pad channels 6,7 -> zero (avoid NaN garbage into MFMA)
          *(unsigned int*)&sh[addr]     = 0u;
          *(unsigned int*)&sh[addr + 8] = 0u;
        }
      }
    }
    if (tid < 16) ((unsigned int*)sh)[2880 + tid] = 0u;  // tail overrun pad
  }
  __syncthreads();

  const int lane = tid & 63;
  const int w    = tid >> 6;    // wave 0..3 -> output rows w*8..w*8+7
  const int q    = lane >> 4;   // k-group / pixel-quad
  const int ocl  = lane & 15;   // output channel (B col / C col)

  // ---- B fragments (pre-swizzled), 10 x 16B coalesced loads ----
  f16x8 Bf[5][2];
  #pragma unroll
  for (int dy = 0; dy < 5; ++dy) {
    #pragma unroll
    for (int m = 0; m < 2; ++m)
      Bf[dy][m] = *(const f16x8*)(tab + ((size_t)((dy * 2 + m) * 64 + lane)) * 8);
  }

  const float bv = (ocl < 6) ? b3[ocl] : (ocl < 15) ? b4[ocl - 6] : b6[0];
  f32x4 C[8];
  #pragma unroll
  for (int r = 0; r < 8; ++r) C[r] = (f32x4){bv, bv, bv, bv};

  // ---- rolling A-frag window over input rows ----
  const int irbase = w * 8;
  const int voff   = ((lane & 15) + q) * 8;  // halfs; +32 halfs for m=1 (dx+4)
  f16x8 W[5][2];
  #pragma unroll
  for (int i = 0; i < 5; ++i) {
    W[i][0] = *(const f16x8*)&sh[(irbase + i) * 160 + voff];
    W[i][1] = *(const f16x8*)&sh[(irbase + i) * 160 + voff + 32];
  }

  #pragma unroll
  for (int r = 0; r < 8; ++r) {
    #pragma unroll
    for (int dy = 0; dy < 5; ++dy) {
      const int wi = (r + dy) % 5;  // compile-time after unroll
      C[r] = __builtin_amdgcn_mfma_f32_16x16x32_f16(W[wi][0], Bf[dy][0], C[r], 0, 0, 0);
      C[r] = __builtin_amdgcn_mfma_f32_16x16x32_f16(W[wi][1], Bf[dy][1], C[r], 0, 0, 0);
    }
    if (r < 7) {  // slide window: load input row irbase + r + 5
      const int wi = r % 5;
      W[wi][0] = *(const f16x8*)&sh[(irbase + r + 5) * 160 + voff];
      W[wi][1] = *(const f16x8*)&sh[(irbase + r + 5) * 160 + voff + 32];
    }
  }

  // ---- epilogue: act + store (C row = q*4 + reg -> 4 consecutive px) ----
  const size_t obase = ((size_t)b * 16 + ocl) * OH;
  const int px0 = x0 + q * 4;
  #pragma unroll
  for (int r = 0; r < 8; ++r) {
    const int oy = y0 + w * 8 + r;
    if (oy < OH) {
      float* po = out + (obase + oy) * OW + px0;
      *(float2*)po       = make_float2(act(C[r][0]), act(C[r][1]));
      *(float2*)(po + 2) = make_float2(act(C[r][2]), act(C[r][3]));
    }
  }
}

extern "C" void kernel_launch(void* const* d_in, const int* in_sizes, int n_in,
                              void* d_out, int out_size, void* d_ws, size_t ws_size,
                              hipStream_t stream) {
  const float* x  = (const float*)d_in[0];
  const float* w3 = (const float*)d_in[1];
  const float* b3 = (const float*)d_in[2];
  const float* w4 = (const float*)d_in[3];
  const float* b4 = (const float*)d_in[4];
  const float* w6 = (const float*)d_in[5];
  const float* b6 = (const float*)d_in[6];
  float* out = (float*)d_out;
  _Float16* tab = (_Float16*)d_ws;  // 5120 halfs = 10 KiB

  hipLaunchKernelGGL(wprep_kernel, dim3(20), dim3(256), 0, stream, w3, w4, w6, tab);

  dim3 grid(9, 5, 256);   // x-tiles (16 px, last shifted), y-tiles (32 rows, masked), batch
  hipLaunchKernelGGL(c3_mfma, grid, dim3(256), 0, stream, x, b3, b4, b6, tab, out);
}

// Round 6
// 200.027 us; speedup vs baseline: 1.1185x; 1.1185x over previous
//
#include <hip/hip_runtime.h>
#include <hip/hip_bf16.h>

// C3 partial connection via MFMA (fp16 in / fp32 acc), wave-independent form.
// y = conv5x5(channel-subsets) + bias; out = 1.7159*tanh(2/3*y).
// M = 16 consecutive x-pixels, N = 16 output channels, K = dx*8 + c (c pad 6->8),
// two mfma_f32_16x16x32_f16 per (row, dy): m=0 dx0..3, m=1 dx4 (rest zero-wt).
//
// R6: NO __syncthreads. Each wave stages its OWN 16 input rows x 20 px x 8 ch
// into a private LDS region (5184 B incl. tail pad), waits lgkmcnt(0) once,
// then computes 12 output rows (120 MFMA, 6-row rolling window, row pairs)
// and stores. 4 waves/block, all fully independent -> cross-phase overlap at
// wave granularity instead of barrier-synced block phases.

#define IH 142
#define IW 142
#define OH 138
#define OW 138
#define WROWS 12        // output rows per wave
#define WSTRIDE 2592    // halfs per wave LDS region: 16 rows * 160 + 32 pad

typedef _Float16 f16x8 __attribute__((ext_vector_type(8)));
typedef float f32x4 __attribute__((ext_vector_type(4)));

// WIDX[oc][c] = src*64 + block-index, or -1. src 0=w3(6,3,5,5) 1=w4(9,4,5,5)
// 2=w6(1,6,5,5); weight elem = blk*25 + dy*5 + dx.
__device__ __constant__ const short WIDX16[16][6] = {
  {   0,    1,    2,   -1,   -1,   -1},   // oc0  {0,1,2}
  {  -1,    3,    4,    5,   -1,   -1},   // oc1  {1,2,3}
  {  -1,   -1,    6,    7,    8,   -1},   // oc2  {2,3,4}
  {  -1,   -1,   -1,    9,   10,   11},   // oc3  {3,4,5}
  {  12,   -1,   -1,   -1,   13,   14},   // oc4  {0,4,5}
  {  15,   16,   -1,   -1,   -1,   17},   // oc5  {0,1,5}
  {64+0, 64+1, 64+2, 64+3,   -1,   -1},   // oc6  {0,1,2,3}
  {  -1, 64+4, 64+5, 64+6, 64+7,   -1},   // oc7  {1,2,3,4}
  {  -1,   -1, 64+8, 64+9, 64+10, 64+11}, // oc8  {2,3,4,5}
  {64+12,  -1,   -1, 64+13, 64+14, 64+15},// oc9  {0,3,4,5}
  {64+16, 64+17, -1,   -1, 64+18, 64+19}, // oc10 {0,1,4,5}
  {64+20, 64+21, 64+22, -1,  -1, 64+23},  // oc11 {0,1,2,5}
  {64+24, 64+25, -1, 64+26, 64+27,  -1},  // oc12 {0,1,3,4}
  {  -1, 64+28, 64+29, -1, 64+30, 64+31}, // oc13 {1,2,4,5}
  {64+32,  -1, 64+33, 64+34, -1, 64+35},  // oc14 {0,2,3,5}
  {128+0, 128+1, 128+2, 128+3, 128+4, 128+5}, // oc15 {0..5}
};

// prep: per-lane pre-swizzled B fragments, 5 dy x 2 m x 64 lanes x 8 halfs.
__global__ void wprep_kernel(const float* __restrict__ w3, const float* __restrict__ w4,
                             const float* __restrict__ w6, _Float16* __restrict__ tab) {
  int t = blockIdx.x * 256 + threadIdx.x;
  if (t >= 5120) return;
  int j = t & 7, lane = (t >> 3) & 63, dm = t >> 9;
  int dy = dm >> 1, m = dm & 1;
  int q = lane >> 4, oc = lane & 15;
  int k = m * 32 + q * 8 + j;
  int dx = k >> 3, c = k & 7;
  float v = 0.f;
  if (c < 6 && dx < 5) {
    int e = WIDX16[oc][c];
    if (e >= 0) {
      int src = e >> 6, blk = e & 63;
      const float* wp = (src == 0) ? w3 : (src == 1) ? w4 : w6;
      v = wp[blk * 25 + dy * 5 + dx];
    }
  }
  tab[t] = (_Float16)v;
}

__device__ __forceinline__ unsigned int pkh(float a, float b) {
  _Float16 ha = (_Float16)a, hb = (_Float16)b;
  unsigned short ua = __builtin_bit_cast(unsigned short, ha);
  unsigned short ub = __builtin_bit_cast(unsigned short, hb);
  return (unsigned int)ua | ((unsigned int)ub << 16);
}

__device__ __forceinline__ float act(float y) {
  const float TS = 1.9235933878519512f;  // 2*(2/3)*log2(e)
  const float e = __builtin_amdgcn_exp2f(y * TS);
  return fmaf(-2.f * 1.7159f, __builtin_amdgcn_rcpf(e + 1.f), 1.7159f);
}

// Block: 256 threads = 4 independent waves; wave w -> output rows y0+w*12..+11,
// 16 px wide. Grid: (9 x-tiles shifted, 3 y-tiles {0,48,90}, 256 images).
__global__ __launch_bounds__(256, 4)
void c3_mfma(const float* __restrict__ x,
             const float* __restrict__ b3, const float* __restrict__ b4,
             const float* __restrict__ b6, const _Float16* __restrict__ tab,
             float* __restrict__ out) {
  __shared__ __attribute__((aligned(16))) _Float16 sh[4 * WSTRIDE];  // 20736 B

  const int tid  = threadIdx.x;
  const int lane = tid & 63;
  const int w    = tid >> 6;
  const int b    = blockIdx.z;
  const int x0   = min((int)blockIdx.x * 16, OW - 16);  // {0,16,...,112,122}
  const int y0   = min((int)blockIdx.y * 48, OH - 48);  // {0,48,90}
  const int ry0  = y0 + w * WROWS;                      // wave's first row

  const int ocl = lane & 15;
  const int q   = lane >> 4;

  // ---- B fragments (independent, issue first) ----
  f16x8 Bf[5][2];
  #pragma unroll
  for (int dy = 0; dy < 5; ++dy)
    #pragma unroll
    for (int m = 0; m < 2; ++m)
      Bf[dy][m] = *(const f16x8*)(tab + ((size_t)((dy * 2 + m) * 64 + lane)) * 8);

  const float bv = (ocl < 6) ? b3[ocl] : (ocl < 15) ? b4[ocl - 6] : b6[0];

  // ---- wave-private staging: 16 rows x 20 px x 8 ch halfs ----
  _Float16* __restrict__ shw = sh + w * WSTRIDE;
  // zero own 32-half tail pad (read by m=1 frags of last rows, x zero-weight)
  if (lane < 16) ((unsigned int*)shw)[1280 + lane] = 0u;

  const float* xb = x + (size_t)b * 6 * IH * IW;
  #pragma unroll
  for (int it = 0; it < 10; ++it) {
    const int idx = it * 64 + lane;          // 0..639: c2(4) x row(16) x px2(10)
    const int c2  = idx / 160;
    const int rem = idx - c2 * 160;
    const int row = rem / 10;
    const int px2 = rem - row * 10;
    const int ha  = row * 160 + px2 * 16 + c2 * 2;   // half index
    if (c2 < 3) {
      const float* pa = xb + ((size_t)(2 * c2) * IH + (ry0 + row)) * IW + x0 + 2 * px2;
      const float* pb = pa + (size_t)IH * IW;
      const float2 va = *(const float2*)pa;
      const float2 vb = *(const float2*)pb;
      *(unsigned int*)&shw[ha]     = pkh(va.x, vb.x);
      *(unsigned int*)&shw[ha + 8] = pkh(va.y, vb.y);
    } else {  // pad channels 6,7 -> zero
      *(unsigned int*)&shw[ha]     = 0u;
      *(unsigned int*)&shw[ha + 8] = 0u;
    }
  }
  // Wave-level LDS visibility: all 64 lanes' ds_writes complete, no barrier.
  asm volatile("s_waitcnt lgkmcnt(0)" ::: "memory");

  // ---- rolling 6-row A-window, row-pair MFMA ----
  const int voff = (ocl + q) * 8;  // halfs; +32 halfs for m=1 (dx+4)
  f16x8 W[6][2];
  #pragma unroll
  for (int i = 0; i < 6; ++i) {
    W[i][0] = *(const f16x8*)&shw[i * 160 + voff];
    W[i][1] = *(const f16x8*)&shw[i * 160 + voff + 32];
  }

  const size_t obase = ((size_t)b * 16 + ocl) * OH;
  #pragma unroll
  for (int r = 0; r < WROWS; r += 2) {
    f32x4 C0 = {bv, bv, bv, bv};
    f32x4 C1 = {bv, bv, bv, bv};
    #pragma unroll
    for (int dy = 0; dy < 5; ++dy) {
      const int i0 = (r + dy) % 6;       // compile-time after unroll
      const int i1 = (r + 1 + dy) % 6;
      C0 = __builtin_amdgcn_mfma_f32_16x16x32_f16(W[i0][0], Bf[dy][0], C0, 0, 0, 0);
      C1 = __builtin_amdgcn_mfma_f32_16x16x32_f16(W[i1][0], Bf[dy][0], C1, 0, 0, 0);
      C0 = __builtin_amdgcn_mfma_f32_16x16x32_f16(W[i0][1], Bf[dy][1], C0, 0, 0, 0);
      C1 = __builtin_amdgcn_mfma_f32_16x16x32_f16(W[i1][1], Bf[dy][1], C1, 0, 0, 0);
    }
    if (r + 2 < WROWS) {  // slide window: rows r+6, r+7
      W[r % 6][0]       = *(const f16x8*)&shw[(r + 6) * 160 + voff];
      W[r % 6][1]       = *(const f16x8*)&shw[(r + 6) * 160 + voff + 32];
      W[(r + 1) % 6][0] = *(const f16x8*)&shw[(r + 7) * 160 + voff];
      W[(r + 1) % 6][1] = *(const f16x8*)&shw[(r + 7) * 160 + voff + 32];
    }
    // store rows r, r+1 (always in-bounds: tiles cover OH/OW exactly)
    {
      float* p0 = out + (obase + (ry0 + r)) * OW + x0 + q * 4;
      float* p1 = out + (obase + (ry0 + r + 1)) * OW + x0 + q * 4;
      *(float2*)p0       = make_float2(act(C0[0]), act(C0[1]));
      *(float2*)(p0 + 2) = make_float2(act(C0[2]), act(C0[3]));
      *(float2*)p1       = make_float2(act(C1[0]), act(C1[1]));
      *(float2*)(p1 + 2) = make_float2(act(C1[2]), act(C1[3]));
    }
  }
}

extern "C" void kernel_launch(void* const* d_in, const int* in_sizes, int n_in,
                              void* d_out, int out_size, void* d_ws, size_t ws_size,
                              hipStream_t stream) {
  const float* x  = (const float*)d_in[0];
  const float* w3 = (const float*)d_in[1];
  const float* b3 = (const float*)d_in[2];
  const float* w4 = (const float*)d_in[3];
  const float* b4 = (const float*)d_in[4];
  const float* w6 = (const float*)d_in[5];
  const float* b6 = (const float*)d_in[6];
  float* out = (float*)d_out;
  _Float16* tab = (_Float16*)d_ws;  // 5120 halfs = 10 KiB

  hipLaunchKernelGGL(wprep_kernel, dim3(20), dim3(256), 0, stream, w3, w4, w6, tab);

  dim3 grid(9, 3, 256);   // x-tiles (16 px, last shifted), y-tiles (48 rows), batch
  hipLaunchKernelGGL(c3_mfma, grid, dim3(256), 0, stream, x, b3, b4, b6, tab, out);
}